// Round 1
// baseline (338.966 us; speedup 1.0000x reference)
//
#include <hip/hip_runtime.h>
#include <hip/hip_bf16.h>

typedef __attribute__((ext_vector_type(8))) short s16x8;   // 8 bf16 (4 VGPRs)
typedef __attribute__((ext_vector_type(4))) float f32x4;
typedef unsigned short u16;
typedef unsigned int u32;

#define SDIM 2048
#define BDIM 2
#define HDIM 12
#define DDIM 64
#define EDIM 768
#define MDIM 4096          // S*B rows
#define SCALE_Q 0.125f     // D^-0.5

static __device__ __forceinline__ f32x4 zero4() {
    f32x4 v; v[0] = v[1] = v[2] = v[3] = 0.f; return v;
}

// fp32 -> bf16 bits, round-to-nearest-even (no NaN inputs in this problem)
static __device__ __forceinline__ u16 f2b(float x) {
    u32 u = __builtin_bit_cast(u32, x);
    u32 lsb = (u >> 16) & 1u;
    u += 0x7fffu + lsb;
    return (u16)(u >> 16);
}

static __device__ __forceinline__ f32x4 mfma16(s16x8 a, s16x8 b, f32x4 c) {
    return __builtin_amdgcn_mfma_f32_16x16x32_bf16(a, b, c, 0, 0, 0);
}

// ---------------------------------------------------------------------------
// key_padding_mask arrives with unknown storage (bool bytes / int32 / float32).
// Detect encoding from bit patterns (deterministic) and normalize to int32.
// Only the first 4096 BYTES are guaranteed valid, so the probe reads 1024 u32s.
// ---------------------------------------------------------------------------
__global__ void mask_norm_kernel(const u32* __restrict__ raw, int* __restrict__ out) {
    __shared__ int okInt, okFloat;
    int t = threadIdx.x;
    if (t == 0) { okInt = 1; okFloat = 1; }
    __syncthreads();
    int li = 1, lf = 1;
    for (int i = t; i < 1024; i += blockDim.x) {
        u32 v = raw[i];
        if (v > 1u) li = 0;
        if (v != 0u && v != 0x3F800000u) lf = 0;
    }
    if (!li) atomicAnd(&okInt, 0);
    if (!lf) atomicAnd(&okFloat, 0);
    __syncthreads();
    const unsigned char* rb = (const unsigned char*)raw;
    for (int i = t; i < BDIM * SDIM; i += blockDim.x) {
        int v;
        if (okInt)        v = (int)raw[i];            // int32 storage, values 0/1
        else if (okFloat) v = (raw[i] != 0u) ? 1 : 0; // float32 storage 0.0/1.0
        else              v = (int)rb[i];             // 1-byte bool storage
        out[i] = v;
    }
}

// ---------------------------------------------------------------------------
// C = (A @ W^T + bias) * scale.  A: MDIMxEDIM (fp32 or bf16), W: EDIMxEDIM fp32.
// scatter=1: write bf16 to [b*H+h][s][d] head layout (QKV path)
// scatter=0: write fp32 row-major MDIMxEDIM (final output path)
// Tile 64x64, BK=32, 4 waves (2x2 of 32x32 per wave).
// Both fragments loaded with the same k-index function -> k-permutation cancels.
// ---------------------------------------------------------------------------
__global__ __launch_bounds__(256) void gemm_xwT(
    const float* __restrict__ Af, const u16* __restrict__ Ab, int a_bf16,
    const float* __restrict__ W, const float* __restrict__ bias, float scale,
    u16* __restrict__ out_sc, float* __restrict__ out_rm, int scatter)
{
    __shared__ u16 Al[64 * 56];   // stride 56 (112B): 2-way LDS conflict max
    __shared__ u16 Bl[64 * 56];
    int tid = threadIdx.x;
    int mb = blockIdx.x * 64, nb = blockIdx.y * 64;
    int lane = tid & 63, w = tid >> 6;
    int r16 = lane & 15, g4 = lane >> 4;
    int wm = w >> 1, wn = w & 1;

    f32x4 acc[2][2];
    acc[0][0] = zero4(); acc[0][1] = zero4(); acc[1][0] = zero4(); acc[1][1] = zero4();

    int srow = tid >> 2, scol = (tid & 3) * 8;   // staging: 8 elems/thread

    for (int kb = 0; kb < EDIM; kb += 32) {
        __syncthreads();
        if (a_bf16) {
            *(uint4*)&Al[srow * 56 + scol] =
                *(const uint4*)&Ab[(size_t)(mb + srow) * EDIM + kb + scol];
        } else {
            const float* s = Af + (size_t)(mb + srow) * EDIM + kb + scol;
            float4 x0 = *(const float4*)s, x1 = *(const float4*)(s + 4);
            u16* d = &Al[srow * 56 + scol];
            d[0] = f2b(x0.x); d[1] = f2b(x0.y); d[2] = f2b(x0.z); d[3] = f2b(x0.w);
            d[4] = f2b(x1.x); d[5] = f2b(x1.y); d[6] = f2b(x1.z); d[7] = f2b(x1.w);
        }
        {
            const float* s = W + (size_t)(nb + srow) * EDIM + kb + scol;
            float4 x0 = *(const float4*)s, x1 = *(const float4*)(s + 4);
            u16* d = &Bl[srow * 56 + scol];
            d[0] = f2b(x0.x); d[1] = f2b(x0.y); d[2] = f2b(x0.z); d[3] = f2b(x0.w);
            d[4] = f2b(x1.x); d[5] = f2b(x1.y); d[6] = f2b(x1.z); d[7] = f2b(x1.w);
        }
        __syncthreads();
        s16x8 a[2], bb[2];
        #pragma unroll
        for (int mi = 0; mi < 2; ++mi)
            a[mi] = *(const s16x8*)&Al[(wm * 32 + mi * 16 + r16) * 56 + g4 * 8];
        #pragma unroll
        for (int ni = 0; ni < 2; ++ni)
            bb[ni] = *(const s16x8*)&Bl[(wn * 32 + ni * 16 + r16) * 56 + g4 * 8];
        #pragma unroll
        for (int mi = 0; mi < 2; ++mi)
            #pragma unroll
            for (int ni = 0; ni < 2; ++ni)
                acc[mi][ni] = mfma16(a[mi], bb[ni], acc[mi][ni]);
    }

    #pragma unroll
    for (int mi = 0; mi < 2; ++mi) {
        #pragma unroll
        for (int ni = 0; ni < 2; ++ni) {
            int n = nb + wn * 32 + ni * 16 + r16;
            float bv = bias[n];
            #pragma unroll
            for (int r = 0; r < 4; ++r) {
                int m = mb + wm * 32 + mi * 16 + g4 * 4 + r;
                float c = (acc[mi][ni][r] + bv) * scale;
                if (scatter) {
                    int s_ = m >> 1, b_ = m & 1, h_ = n >> 6, d_ = n & 63;
                    out_sc[((size_t)(b_ * HDIM + h_) * SDIM + s_) * DDIM + d_] = f2b(c);
                } else {
                    out_rm[(size_t)m * EDIM + n] = c;
                }
            }
        }
    }
}

// ---------------------------------------------------------------------------
// Fused flash attention. One wave per (bh, 16 q-rows). Online softmax.
// Score tile layout D[q][k]: row=q=(lane>>4)*4+r, col=k=lane&15 (verified C/D map).
// bias streamed from global (64B-coalesced per 16-lane group), V staged in LDS.
// Masked scores -> -1e30 (self-correcting online-softmax poison).
// ---------------------------------------------------------------------------
__global__ __launch_bounds__(64) void attn_fused(
    const u16* __restrict__ qw, const u16* __restrict__ kw,
    const u16* __restrict__ vw, const float* __restrict__ bias,
    const int* __restrict__ maskI, u16* __restrict__ attn_out)
{
    __shared__ u16 Vl[32 * 64];
    __shared__ u16 Pl[16 * 56];
    int qt = blockIdx.x, bh = blockIdx.y;
    int lane = threadIdx.x;
    int r16 = lane & 15, g4 = lane >> 4;
    int qbase = qt * 16;
    int b_ = bh / HDIM, h_ = bh % HDIM;
    const u16* Q  = qw + (size_t)bh * SDIM * DDIM;
    const u16* Kp = kw + (size_t)bh * SDIM * DDIM;
    const u16* Vp = vw + (size_t)bh * SDIM * DDIM;
    const float* Brow = bias + (size_t)bh * SDIM * SDIM;
    const int* mrow = maskI + b_ * SDIM;

    s16x8 qf[2];
    qf[0] = *(const s16x8*)&Q[(size_t)(qbase + r16) * DDIM + g4 * 8];
    qf[1] = *(const s16x8*)&Q[(size_t)(qbase + r16) * DDIM + g4 * 8 + 32];

    f32x4 accO[4];
    float m_run[4], l_run[4], alpha[4];
    #pragma unroll
    for (int dt = 0; dt < 4; ++dt) accO[dt] = zero4();
    #pragma unroll
    for (int r = 0; r < 4; ++r) { m_run[r] = -1e30f; l_run[r] = 0.f; }

    for (int kb = 0; kb < SDIM; kb += 32) {
        // stage V tile 32x64 bf16 (each lane copies half a row, 64B)
        {
            int row = lane >> 1, half = (lane & 1) * 32;
            const uint4* s = (const uint4*)&Vp[(size_t)(kb + row) * DDIM + half];
            uint4* d = (uint4*)&Vl[row * 64 + half];
            d[0] = s[0]; d[1] = s[1]; d[2] = s[2]; d[3] = s[3];
        }
        // QK^T: two 16x16 score tiles (k-chunks), contraction over d=64 in 2 MFMAs
        f32x4 sc[2];
        #pragma unroll
        for (int kt = 0; kt < 2; ++kt) {
            f32x4 a = zero4();
            #pragma unroll
            for (int c = 0; c < 2; ++c) {
                s16x8 kf = *(const s16x8*)&Kp[(size_t)(kb + kt * 16 + r16) * DDIM + g4 * 8 + c * 32];
                a = mfma16(qf[c], kf, a);
            }
            sc[kt] = a;
        }
        // bias + key-padding mask (q pre-scaled in projection)
        #pragma unroll
        for (int kt = 0; kt < 2; ++kt) {
            int kcol = kb + kt * 16 + r16;
            bool msk = (mrow[kcol] != 0);
            #pragma unroll
            for (int r = 0; r < 4; ++r) {
                float sv = sc[kt][r] + Brow[(size_t)(qbase + g4 * 4 + r) * SDIM + kcol];
                sc[kt][r] = msk ? -1e30f : sv;
            }
        }
        // online softmax over this 32-key block (row = q lives across the 16 lanes
        // of a lane-group; xor masks 1..8 stay inside the group)
        #pragma unroll
        for (int r = 0; r < 4; ++r) {
            float bm = fmaxf(sc[0][r], sc[1][r]);
            #pragma unroll
            for (int off = 1; off < 16; off <<= 1) bm = fmaxf(bm, __shfl_xor(bm, off));
            float mn = fmaxf(m_run[r], bm);
            alpha[r] = __expf(m_run[r] - mn);
            float p0 = __expf(sc[0][r] - mn);
            float p1 = __expf(sc[1][r] - mn);
            float ps = p0 + p1;
            #pragma unroll
            for (int off = 1; off < 16; off <<= 1) ps += __shfl_xor(ps, off);
            l_run[r] = l_run[r] * alpha[r] + ps;
            m_run[r] = mn;
            Pl[(g4 * 4 + r) * 56 + r16]      = f2b(p0);
            Pl[(g4 * 4 + r) * 56 + 16 + r16] = f2b(p1);
        }
        #pragma unroll
        for (int dt = 0; dt < 4; ++dt) {
            accO[dt][0] *= alpha[0];
            accO[dt][1] *= alpha[1];
            accO[dt][2] *= alpha[2];
            accO[dt][3] *= alpha[3];
        }
        __syncthreads();
        // PV: A = P[q][k] from LDS, B = V[k][d] from LDS (same k-index function g)
        s16x8 pf = *(const s16x8*)&Pl[r16 * 56 + g4 * 8];
        #pragma unroll
        for (int dt = 0; dt < 4; ++dt) {
            s16x8 vf;
            #pragma unroll
            for (int i = 0; i < 8; ++i) vf[i] = (short)Vl[(g4 * 8 + i) * 64 + dt * 16 + r16];
            accO[dt] = mfma16(pf, vf, accO[dt]);
        }
        __syncthreads();
    }
    // epilogue: normalize and write attn in (s,b,e) layout (bf16)
    #pragma unroll
    for (int dt = 0; dt < 4; ++dt) {
        #pragma unroll
        for (int r = 0; r < 4; ++r) {
            float o = accO[dt][r] / l_run[r];
            int q = qbase + g4 * 4 + r;
            attn_out[((size_t)q * BDIM + b_) * EDIM + h_ * DDIM + dt * 16 + r16] = f2b(o);
        }
    }
}

extern "C" void kernel_launch(void* const* d_in, const int* in_sizes, int n_in,
                              void* d_out, int out_size, void* d_ws, size_t ws_size,
                              hipStream_t stream) {
    const float* query     = (const float*)d_in[0];
    const float* attn_bias = (const float*)d_in[1];
    const u32*   mask_raw  = (const u32*)d_in[2];
    const float* Wq = (const float*)d_in[3];
    const float* bq = (const float*)d_in[4];
    const float* Wk = (const float*)d_in[5];
    const float* bk = (const float*)d_in[6];
    const float* Wv = (const float*)d_in[7];
    const float* bv = (const float*)d_in[8];
    const float* Wo = (const float*)d_in[9];
    const float* bo = (const float*)d_in[10];
    float* out = (float*)d_out;

    // workspace layout: mask(16KB) | q | k | v | attn   (bf16 head tensors)
    char* ws = (char*)d_ws;
    int* maskI = (int*)ws;
    const size_t HEADSZ = (size_t)BDIM * HDIM * SDIM * DDIM;  // 3,145,728 elems
    u16* qws = (u16*)(ws + 16384);
    u16* kws = qws + HEADSZ;
    u16* vws = kws + HEADSZ;
    u16* aws = vws + HEADSZ;

    mask_norm_kernel<<<1, 256, 0, stream>>>(mask_raw, maskI);

    dim3 gg(MDIM / 64, EDIM / 64);
    gemm_xwT<<<gg, 256, 0, stream>>>(query, nullptr, 0, Wq, bq, SCALE_Q, qws, nullptr, 1);
    gemm_xwT<<<gg, 256, 0, stream>>>(query, nullptr, 0, Wk, bk, 1.0f,    kws, nullptr, 1);
    gemm_xwT<<<gg, 256, 0, stream>>>(query, nullptr, 0, Wv, bv, 1.0f,    vws, nullptr, 1);

    dim3 ga(SDIM / 16, BDIM * HDIM);
    attn_fused<<<ga, 64, 0, stream>>>(qws, kws, vws, attn_bias, maskI, aws);

    gemm_xwT<<<gg, 256, 0, stream>>>(nullptr, aws, 1, Wo, bo, 1.0f, nullptr, out, 0);
}